// Round 1
// 5525.380 us; speedup vs baseline: 1.9057x; 1.9057x over previous
//
#include <hip/hip_runtime.h>

typedef unsigned short bf16_t;

#define HH 256
#define WW 256
#define ZZ 256
#define NELEM 33554432          /* 2*256^3 elements */
#define BLK   256
#define GRD   ((NELEM / 4) / BLK)   /* 32768 blocks; 4 f32 elems per thread */
#define EPSD  1e-6

// ---------- bf16 <-> f32 (for reduced-precision scratch fields only) ----------
__device__ __forceinline__ float bf2f(unsigned int s) {
    union { unsigned int u; float f; } c; c.u = s << 16; return c.f;
}
__device__ __forceinline__ unsigned int f2bf(float f) {
    union { float f; unsigned int u; } c; c.f = f;
    return (c.u + 0x7fffu + ((c.u >> 16) & 1u)) >> 16;   // RNE
}

// ---------- overloaded 4-wide field I/O ----------
__device__ __forceinline__ void ld4(const float* F, int e, float* o) {
    float4 v = *(const float4*)(F + e);
    o[0] = v.x; o[1] = v.y; o[2] = v.z; o[3] = v.w;
}
__device__ __forceinline__ void st4(float* F, int e, const float* o) {
    *(float4*)(F + e) = make_float4(o[0], o[1], o[2], o[3]);
}
__device__ __forceinline__ void ld4(const bf16_t* F, int e, float* o) {
    uint2 u = *(const uint2*)(F + e);
    o[0] = bf2f(u.x & 0xffffu); o[1] = bf2f(u.x >> 16);
    o[2] = bf2f(u.y & 0xffffu); o[3] = bf2f(u.y >> 16);
}
__device__ __forceinline__ void st4(bf16_t* F, int e, const float* o) {
    uint2 u;
    u.x = f2bf(o[0]) | (f2bf(o[1]) << 16);
    u.y = f2bf(o[2]) | (f2bf(o[3]) << 16);
    *(uint2*)(F + e) = u;
}
__device__ __forceinline__ float lds1(const float* F, int e)  { return F[e]; }
__device__ __forceinline__ float lds1(const bf16_t* F, int e) { return bf2f(F[e]); }
__device__ __forceinline__ void zero4(float* o) {
#pragma unroll
    for (int i = 0; i < 4; ++i) o[i] = 0.f;
}

// 7-point stencil, zero Dirichlet boundaries; c[] = already-loaded center row.
template<typename T>
__device__ __forceinline__ void stencil4(const T* F, int e, int w, int h, int z,
                                         float cw, const float* c, float* out) {
    float wm[4], wp[4], hm[4], hp[4];
    if (w > 0)      ld4(F, e - ZZ, wm);      else zero4(wm);
    if (w < WW - 1) ld4(F, e + ZZ, wp);      else zero4(wp);
    if (h > 0)      ld4(F, e - WW * ZZ, hm); else zero4(hm);
    if (h < HH - 1) ld4(F, e + WW * ZZ, hp); else zero4(hp);
    float zm = (z > 0)      ? lds1(F, e - 1) : 0.f;
    float zp = (z < ZZ - 4) ? lds1(F, e + 4) : 0.f;
#pragma unroll
    for (int i = 0; i < 4; ++i) {
        float left  = (i == 0) ? zm : c[i - 1];
        float right = (i == 3) ? zp : c[i + 1];
        out[i] = cw * c[i] - left - right - wm[i] - wp[i] - hm[i] - hp[i];
    }
}

__device__ __forceinline__ double dot4d(const float* a, const float* b) {
    double s = 0.0;
#pragma unroll
    for (int i = 0; i < 4; ++i) s += (double)a[i] * (double)b[i];
    return s;
}

// ---------- reductions (f64, one atomic per block, per batch) ----------
__device__ __forceinline__ double wave_red(double v) {
#pragma unroll
    for (int o = 32; o > 0; o >>= 1) v += __shfl_down(v, o, 64);
    return v;
}
__device__ __forceinline__ void block_red1(double v0, double* d0) {
    v0 = wave_red(v0);
    __shared__ double sm0[4];
    int lane = threadIdx.x & 63, wid = threadIdx.x >> 6;
    if (lane == 0) sm0[wid] = v0;
    __syncthreads();
    if (threadIdx.x == 0) atomicAdd(d0, sm0[0] + sm0[1] + sm0[2] + sm0[3]);
}
__device__ __forceinline__ void block_red2(double v0, double v1, double* d0, double* d1) {
    v0 = wave_red(v0); v1 = wave_red(v1);
    __shared__ double sm0[4], sm1[4];
    int lane = threadIdx.x & 63, wid = threadIdx.x >> 6;
    if (lane == 0) { sm0[wid] = v0; sm1[wid] = v1; }
    __syncthreads();
    if (threadIdx.x == 0) {
        atomicAdd(d0, sm0[0] + sm0[1] + sm0[2] + sm0[3]);
        atomicAdd(d1, sm1[0] + sm1[1] + sm1[2] + sm1[3]);
    }
}

#define DECODE()                                            \
    int gid = blockIdx.x * BLK + threadIdx.x;               \
    int e = gid << 2;                                       \
    int z = e & (ZZ - 1);                                   \
    int w = (e >> 8) & (WW - 1);                            \
    int h = (e >> 16) & (HH - 1);                           \
    int bat = e >> 24;

__global__ void k_zero(double* acc) {
    if (threadIdx.x < 128) acc[threadIdx.x] = 0.0;
}

// r0 = b - S(x); rho0 += r0.r0
__global__ void k_init(const float* xf, const float* bf, const float* cen,
                       float* r0, double* accRho0) {
    DECODE();
    float cw = cen[h * WW + w];
    float c[4], st[4], b4[4], r[4];
    ld4(xf, e, c);
    stencil4(xf, e, w, h, z, cw, c, st);
    ld4(bf, e, b4);
#pragma unroll
    for (int i = 0; i < 4; ++i) r[i] = b4[i] - st[i];
    st4(r0, e, r);
    block_red1(dot4d(r, r), &accRho0[bat]);
}

// v = S(p); dot_r0v += r0.v
// (r0 load hoisted ABOVE the v store: all loads precede all stores so the
//  compiler never needs an alias-ordering vmcnt drain mid-kernel.)
template<typename TV>
__global__ void k_spmv(const float* pf, const float* r0, const float* cen,
                       TV* vf, double* accR0V) {
    DECODE();
    float cw = cen[h * WW + w];
    float c[4], st[4], r04[4];
    ld4(pf, e, c);
    ld4(r0, e, r04);
    stencil4(pf, e, w, h, z, cw, c, st);
    st4(vf, e, st);
    block_red1(dot4d(r04, st), &accR0V[bat]);
}

// a = rho/(r0.v+eps); s = r - a*v; t = S(r) - a*S(v)  (stencil linearity);
// store t (bf16); dot_ts += t.s; dot_tt += t.t
template<typename TV>
__global__ void k_st(const float* rf, const TV* vf, const float* cen, bf16_t* tf,
                     const double* aRho, const double* aR0V,
                     double* aTS, double* aTT) {
    DECODE();
    float cw = cen[h * WW + w];
    float a = (float)(aRho[bat] / (aR0V[bat] + EPSD));
    float rc[4], vc[4], str[4], stv[4], s4[4], t4[4];
    ld4(rf, e, rc);
    ld4(vf, e, vc);
    stencil4(rf, e, w, h, z, cw, rc, str);
    stencil4(vf, e, w, h, z, cw, vc, stv);
#pragma unroll
    for (int i = 0; i < 4; ++i) {
        s4[i] = rc[i] - a * vc[i];
        t4[i] = str[i] - a * stv[i];
    }
    st4(tf, e, t4);
    block_red2(dot4d(t4, s4), dot4d(t4, t4), &aTS[bat], &aTT[bat]);
}

// x' = x + a*p + o*s; r' = s - o*t; rho_next += r0.r'   (pure elementwise)
// NOTE: no __restrict__ — xin/rout alias on iter 0, xin/xout and rf/rout on
// iters>=1; same-index read-then-write. ALL loads (incl. r0) are issued before
// any store so program-order aliasing constraints impose no waits.
template<typename TV>
__global__ void k_update(const float* xin, float* xout, const float* pf,
                         const float* rf, float* rout, const TV* vf,
                         const bf16_t* tf, const float* r0f,
                         const double* aRho, const double* aR0V,
                         const double* aTS, const double* aTT,
                         double* aRhoN, int storeR) {
    DECODE();
    (void)z; (void)w; (void)h;
    float a = (float)(aRho[bat] / (aR0V[bat] + EPSD));
    float o = (float)(aTS[bat] / (aTT[bat] + EPSD));
    float x4[4], p4[4], r4[4], v4[4], t4[4], s4[4], xo[4], rn[4], r04[4];
    ld4(xin, e, x4); ld4(pf, e, p4); ld4(rf, e, r4);
    ld4(vf, e, v4);  ld4(tf, e, t4);
    if (storeR) ld4(r0f, e, r04);           // hoisted above all stores
#pragma unroll
    for (int i = 0; i < 4; ++i) {
        s4[i] = r4[i] - a * v4[i];
        xo[i] = x4[i] + a * p4[i] + o * s4[i];
        rn[i] = s4[i] - o * t4[i];
    }
    st4(xout, e, xo);
    if (storeR) {
        st4(rout, e, rn);
        block_red1(dot4d(r04, rn), &aRhoN[bat]);
    }
}

// beta = rhoN/(rho+eps) * a/(o+eps); p' = r' + beta*(p - o*v)
// (pin/pout alias on iters >= 1 — no __restrict__)
template<typename TV>
__global__ void k_pupd(const float* rf, const float* pin, const TV* vf, float* pout,
                       const double* aRho, const double* aR0V,
                       const double* aTS, const double* aTT,
                       const double* aRhoN) {
    DECODE();
    (void)z; (void)w; (void)h;
    double alpha = aRho[bat] / (aR0V[bat] + EPSD);
    double omega = aTS[bat] / (aTT[bat] + EPSD);
    float bt = (float)(aRhoN[bat] / (aRho[bat] + EPSD) * (alpha / (omega + EPSD)));
    float o = (float)omega;
    float r4[4], p4[4], v4[4], pn[4];
    ld4(rf, e, r4); ld4(pin, e, p4); ld4(vf, e, v4);
#pragma unroll
    for (int i = 0; i < 4; ++i) pn[i] = r4[i] + bt * (p4[i] - o * v4[i]);
    st4(pout, e, pn);
}

// ---------------------------------------------------------------------------
// acc slot layout: 8 units of 128 B (fits the existing 1024 B reservation).
// Invariant: within every kernel, the unit holding its atomic TARGET is
// disjoint from the units holding its broadcast READS. Previously all slots
// were packed into 272 B, so k_update's per-thread read of rho_i shared a
// cache line with the rho_{i+1} atomic hammered by 32768 blocks -> the
// broadcast loads serialized into the device-scope RMW chain (363 GB/s,
// VALUBusy 1.3%). rho slots alternate units 0/1; r0v -> units 2-3;
// ts -> units 4-5; tt -> units 6-7. Offsets below are in doubles (16 per unit).
//   unit0: rho0@0  rho2@2  rho4@4      unit1: rho1@16 rho3@18
//   unit2: r0v0@32 r0v1@34             unit3: r0v2@48 r0v3@50
//   unit4: ts0@64  ts1@66              unit5: ts2@80  ts3@82
//   unit6: tt0@96  tt1@98              unit7: tt2@112 tt3@114
// Each slot = 2 doubles (batch 0, batch 1).
// ---------------------------------------------------------------------------
static const int RHO_OFF[5] = { 0, 16, 2, 18, 4 };
static const int R0V_OFF[4] = { 32, 34, 48, 50 };
static const int TS_OFF[4]  = { 64, 66, 80, 82 };
static const int TT_OFF[4]  = { 96, 98, 112, 114 };

template<typename TV>
static void run_all(const float* x_in, const float* b_in, const float* cen,
                    float* bufR0, float* bufR, float* bufP, float* x_out,
                    TV* bufV, bf16_t* bufT, double* acc, hipStream_t stream) {
    dim3 blk(BLK), grd(GRD);
    k_zero<<<dim3(1), dim3(128), 0, stream>>>(acc);
    k_init<<<grd, blk, 0, stream>>>(x_in, b_in, cen, bufR0, acc + RHO_OFF[0]);

    const float* rcur = bufR0;   // iter 0: r = p = r0 (aliased reads)
    const float* pcur = bufR0;
    const float* xcur = x_in;
    for (int i = 0; i < 4; ++i) {
        double* aRho  = acc + RHO_OFF[i];
        double* aR0V  = acc + R0V_OFF[i];
        double* aTS   = acc + TS_OFF[i];
        double* aTT   = acc + TT_OFF[i];
        double* aRhoN = acc + RHO_OFF[i + 1];
        k_spmv<TV><<<grd, blk, 0, stream>>>(pcur, bufR0, cen, bufV, aR0V);
        k_st<TV><<<grd, blk, 0, stream>>>(rcur, bufV, cen, bufT, aRho, aR0V, aTS, aTT);
        int storeR = (i < 3) ? 1 : 0;   // final iter: r', rho4, p' dead
        k_update<TV><<<grd, blk, 0, stream>>>(xcur, x_out, pcur, rcur, bufR, bufV,
                                              bufT, bufR0, aRho, aR0V, aTS, aTT,
                                              aRhoN, storeR);
        if (i < 3)
            k_pupd<TV><<<grd, blk, 0, stream>>>(bufR, pcur, bufV, bufP,
                                                aRho, aR0V, aTS, aTT, aRhoN);
        rcur = bufR; pcur = bufP; xcur = x_out;
    }
}

extern "C" void kernel_launch(void* const* d_in, const int* in_sizes, int n_in,
                              void* d_out, int out_size, void* d_ws, size_t ws_size,
                              hipStream_t stream) {
    // All tensors are float32 (per reference dtypes). Field homes:
    //   x  : d_out (f32, in-place across iterations)
    //   r0 : d_in[2] ('ref' input — unused by the math, restored every launch)
    //   r  : d_in[0] (x input; read elementwise in iter-0 k_update before write)
    //   p  : d_in[1] (b input; consumed in k_init)
    //   v  : d_ws (f32 if ws_size allows, else bf16)
    //   t  : d_ws (bf16 always — only feeds r' = s - o*t; 0.2% rel error is fine)
    const float* x_in = (const float*)d_in[0];
    const float* b_in = (const float*)d_in[1];
    const float* cen  = (const float*)d_in[3];
    float* bufR  = (float*)d_in[0];
    float* bufP  = (float*)d_in[1];
    float* bufR0 = (float*)d_in[2];
    float* x_out = (float*)d_out;

    double* acc = (double*)d_ws;
    char* base = (char*)d_ws + 1024;
    const size_t F32F = (size_t)NELEM * 4, BF16F = (size_t)NELEM * 2;

    if (ws_size >= 1024 + F32F + BF16F) {
        // tier B (~201.3 MB): v in f32, t in bf16
        float* bufV = (float*)base;
        bf16_t* bufT = (bf16_t*)(base + F32F);
        run_all<float>(x_in, b_in, cen, bufR0, bufR, bufP, x_out, bufV, bufT,
                       acc, stream);
    } else {
        // tier C (~134.2 MB, proven writable in round 2): v and t in bf16
        bf16_t* bufV = (bf16_t*)base;
        bf16_t* bufT = bufV + NELEM;
        run_all<bf16_t>(x_in, b_in, cen, bufR0, bufR, bufP, x_out, bufV, bufT,
                        acc, stream);
    }
}

// Round 2
// 3792.556 us; speedup vs baseline: 2.7764x; 1.4569x over previous
//
#include <hip/hip_runtime.h>

typedef unsigned short bf16_t;

#define HH 256
#define WW 256
#define ZZ 256
#define NELEM 33554432          /* 2*256^3 elements */
#define BLK   256
#define GRD   ((NELEM / 4) / BLK)   /* 32768 blocks; 4 f32 elems per thread */
#define EPSD  1e-6

// ---------- bf16 <-> f32 (for reduced-precision scratch fields only) ----------
__device__ __forceinline__ float bf2f(unsigned int s) {
    union { unsigned int u; float f; } c; c.u = s << 16; return c.f;
}
__device__ __forceinline__ unsigned int f2bf(float f) {
    union { float f; unsigned int u; } c; c.f = f;
    return (c.u + 0x7fffu + ((c.u >> 16) & 1u)) >> 16;   // RNE
}

// ---------- overloaded 4-wide field I/O ----------
__device__ __forceinline__ void ld4(const float* F, int e, float* o) {
    float4 v = *(const float4*)(F + e);
    o[0] = v.x; o[1] = v.y; o[2] = v.z; o[3] = v.w;
}
__device__ __forceinline__ void st4(float* F, int e, const float* o) {
    *(float4*)(F + e) = make_float4(o[0], o[1], o[2], o[3]);
}
__device__ __forceinline__ void ld4(const bf16_t* F, int e, float* o) {
    uint2 u = *(const uint2*)(F + e);
    o[0] = bf2f(u.x & 0xffffu); o[1] = bf2f(u.x >> 16);
    o[2] = bf2f(u.y & 0xffffu); o[3] = bf2f(u.y >> 16);
}
__device__ __forceinline__ void st4(bf16_t* F, int e, const float* o) {
    uint2 u;
    u.x = f2bf(o[0]) | (f2bf(o[1]) << 16);
    u.y = f2bf(o[2]) | (f2bf(o[3]) << 16);
    *(uint2*)(F + e) = u;
}
__device__ __forceinline__ float lds1(const float* F, int e)  { return F[e]; }
__device__ __forceinline__ float lds1(const bf16_t* F, int e) { return bf2f(F[e]); }
__device__ __forceinline__ void zero4(float* o) {
#pragma unroll
    for (int i = 0; i < 4; ++i) o[i] = 0.f;
}

// 7-point stencil, zero Dirichlet boundaries; c[] = already-loaded center row.
template<typename T>
__device__ __forceinline__ void stencil4(const T* F, int e, int w, int h, int z,
                                         float cw, const float* c, float* out) {
    float wm[4], wp[4], hm[4], hp[4];
    if (w > 0)      ld4(F, e - ZZ, wm);      else zero4(wm);
    if (w < WW - 1) ld4(F, e + ZZ, wp);      else zero4(wp);
    if (h > 0)      ld4(F, e - WW * ZZ, hm); else zero4(hm);
    if (h < HH - 1) ld4(F, e + WW * ZZ, hp); else zero4(hp);
    float zm = (z > 0)      ? lds1(F, e - 1) : 0.f;
    float zp = (z < ZZ - 4) ? lds1(F, e + 4) : 0.f;
#pragma unroll
    for (int i = 0; i < 4; ++i) {
        float left  = (i == 0) ? zm : c[i - 1];
        float right = (i == 3) ? zp : c[i + 1];
        out[i] = cw * c[i] - left - right - wm[i] - wp[i] - hm[i] - hp[i];
    }
}

__device__ __forceinline__ double dot4d(const float* a, const float* b) {
    double s = 0.0;
#pragma unroll
    for (int i = 0; i < 4; ++i) s += (double)a[i] * (double)b[i];
    return s;
}

// ---------------------------------------------------------------------------
// Accumulator region: S replicas of a 1024 B block (replica r at byte r*1024).
// Within each replica, the 8x128B unit layout (round-0 fix) keeps every
// kernel's atomic-target lines disjoint from its broadcast-read lines.
// Replication (S=16) breaks the single-LLC-line f64 atomic chain: previously
// 16384 device-scope RMWs serialized on ONE line (~20 ns each => ~330 us floor
// that dominated every reduction kernel). A block atomics into replica
// (blockIdx.x & (S-1)); consumers sum the S replicas (16 independent L2-hit
// uniform loads, unrolled).  Offsets below in doubles; 128 doubles / replica.
//   unit0: rho0@0  rho2@2  rho4@4      unit1: rho1@16 rho3@18
//   unit2: r0v0@32 r0v1@34             unit3: r0v2@48 r0v3@50
//   unit4: ts0@64  ts1@66              unit5: ts2@80  ts3@82
//   unit6: tt0@96  tt1@98              unit7: tt2@112 tt3@114
// Each slot = 2 doubles (batch 0, batch 1).
// ---------------------------------------------------------------------------
#define REP 128   /* doubles per replica */

template<int S>
__device__ __forceinline__ double rd_acc(const double* acc, int off) {
    double s = 0.0;
#pragma unroll
    for (int i = 0; i < S; ++i) s += acc[i * REP + off];
    return s;
}

// ---------- reductions (f64, one atomic per block, per batch) ----------
__device__ __forceinline__ double wave_red(double v) {
#pragma unroll
    for (int o = 32; o > 0; o >>= 1) v += __shfl_down(v, o, 64);
    return v;
}
__device__ __forceinline__ void block_red1(double v0, double* d0) {
    v0 = wave_red(v0);
    __shared__ double sm0[4];
    int lane = threadIdx.x & 63, wid = threadIdx.x >> 6;
    if (lane == 0) sm0[wid] = v0;
    __syncthreads();
    if (threadIdx.x == 0) atomicAdd(d0, sm0[0] + sm0[1] + sm0[2] + sm0[3]);
}
__device__ __forceinline__ void block_red2(double v0, double v1, double* d0, double* d1) {
    v0 = wave_red(v0); v1 = wave_red(v1);
    __shared__ double sm0[4], sm1[4];
    int lane = threadIdx.x & 63, wid = threadIdx.x >> 6;
    if (lane == 0) { sm0[wid] = v0; sm1[wid] = v1; }
    __syncthreads();
    if (threadIdx.x == 0) {
        atomicAdd(d0, sm0[0] + sm0[1] + sm0[2] + sm0[3]);
        atomicAdd(d1, sm1[0] + sm1[1] + sm1[2] + sm1[3]);
    }
}

#define DECODE()                                            \
    int gid = blockIdx.x * BLK + threadIdx.x;               \
    int e = gid << 2;                                       \
    int z = e & (ZZ - 1);                                   \
    int w = (e >> 8) & (WW - 1);                            \
    int h = (e >> 16) & (HH - 1);                           \
    int bat = e >> 24;

__global__ void k_zero(double* acc, int n) {
    int i = blockIdx.x * 256 + threadIdx.x;
    if (i < n) acc[i] = 0.0;
}

// r0 = b - S(x); rho0 += r0.r0
template<int S>
__global__ void k_init(const float* xf, const float* bf, const float* cen,
                       float* r0, double* acc, int oRho0) {
    DECODE();
    float cw = cen[h * WW + w];
    float c[4], st[4], b4[4], r[4];
    ld4(xf, e, c);
    stencil4(xf, e, w, h, z, cw, c, st);
    ld4(bf, e, b4);
#pragma unroll
    for (int i = 0; i < 4; ++i) r[i] = b4[i] - st[i];
    st4(r0, e, r);
    int sub = blockIdx.x & (S - 1);
    block_red1(dot4d(r, r), &acc[sub * REP + oRho0 + bat]);
}

// v = S(p); dot_r0v += r0.v  (all loads issued before the v store)
template<typename TV, int S>
__global__ void k_spmv(const float* pf, const float* r0, const float* cen,
                       TV* vf, double* acc, int oR0V) {
    DECODE();
    float cw = cen[h * WW + w];
    float c[4], st[4], r04[4];
    ld4(pf, e, c);
    ld4(r0, e, r04);
    stencil4(pf, e, w, h, z, cw, c, st);
    st4(vf, e, st);
    int sub = blockIdx.x & (S - 1);
    block_red1(dot4d(r04, st), &acc[sub * REP + oR0V + bat]);
}

// a = rho/(r0.v+eps); s = r - a*v; t = S(r) - a*S(v)  (stencil linearity);
// store t (bf16); dot_ts += t.s; dot_tt += t.t
template<typename TV, int S>
__global__ void k_st(const float* rf, const TV* vf, const float* cen, bf16_t* tf,
                     double* acc, int oRho, int oR0V, int oTS, int oTT) {
    DECODE();
    float cw = cen[h * WW + w];
    float rc[4], vc[4], str[4], stv[4], s4[4], t4[4];
    ld4(rf, e, rc);
    ld4(vf, e, vc);
    stencil4(rf, e, w, h, z, cw, rc, str);
    stencil4(vf, e, w, h, z, cw, vc, stv);
    double rho = rd_acc<S>(acc, oRho + bat);
    double r0v = rd_acc<S>(acc, oR0V + bat);
    float a = (float)(rho / (r0v + EPSD));
#pragma unroll
    for (int i = 0; i < 4; ++i) {
        s4[i] = rc[i] - a * vc[i];
        t4[i] = str[i] - a * stv[i];
    }
    st4(tf, e, t4);
    int sub = blockIdx.x & (S - 1);
    block_red2(dot4d(t4, s4), dot4d(t4, t4),
               &acc[sub * REP + oTS + bat], &acc[sub * REP + oTT + bat]);
}

// x' = x + a*p + o*s; r' = s - o*t; rho_next += r0.r'   (pure elementwise)
// NOTE: no __restrict__ — xin/rout alias on iter 0, xin/xout and rf/rout on
// iters>=1; same-index read-then-write. ALL field loads are issued before
// any store so program-order aliasing constraints impose no waits.
template<typename TV, int S>
__global__ void k_update(const float* xin, float* xout, const float* pf,
                         const float* rf, float* rout, const TV* vf,
                         const bf16_t* tf, const float* r0f,
                         double* acc, int oRho, int oR0V, int oTS, int oTT,
                         int oRhoN, int storeR) {
    DECODE();
    (void)z; (void)w; (void)h;
    float x4[4], p4[4], r4[4], v4[4], t4[4], s4[4], xo[4], rn[4], r04[4];
    ld4(xin, e, x4); ld4(pf, e, p4); ld4(rf, e, r4);
    ld4(vf, e, v4);  ld4(tf, e, t4);
    if (storeR) ld4(r0f, e, r04);           // hoisted above all stores
    double rho = rd_acc<S>(acc, oRho + bat);
    double r0v = rd_acc<S>(acc, oR0V + bat);
    double ts  = rd_acc<S>(acc, oTS + bat);
    double tt  = rd_acc<S>(acc, oTT + bat);
    float a = (float)(rho / (r0v + EPSD));
    float o = (float)(ts / (tt + EPSD));
#pragma unroll
    for (int i = 0; i < 4; ++i) {
        s4[i] = r4[i] - a * v4[i];
        xo[i] = x4[i] + a * p4[i] + o * s4[i];
        rn[i] = s4[i] - o * t4[i];
    }
    st4(xout, e, xo);
    if (storeR) {
        st4(rout, e, rn);
        int sub = blockIdx.x & (S - 1);
        block_red1(dot4d(r04, rn), &acc[sub * REP + oRhoN + bat]);
    }
}

// beta = rhoN/(rho+eps) * a/(o+eps); p' = r' + beta*(p - o*v)
// (pin/pout alias on iters >= 1 — no __restrict__)
template<typename TV, int S>
__global__ void k_pupd(const float* rf, const float* pin, const TV* vf, float* pout,
                       double* acc, int oRho, int oR0V, int oTS, int oTT,
                       int oRhoN) {
    DECODE();
    (void)z; (void)w; (void)h;
    float r4[4], p4[4], v4[4], pn[4];
    ld4(rf, e, r4); ld4(pin, e, p4); ld4(vf, e, v4);
    double rho  = rd_acc<S>(acc, oRho + bat);
    double r0v  = rd_acc<S>(acc, oR0V + bat);
    double ts   = rd_acc<S>(acc, oTS + bat);
    double tt   = rd_acc<S>(acc, oTT + bat);
    double rhoN = rd_acc<S>(acc, oRhoN + bat);
    double alpha = rho / (r0v + EPSD);
    double omega = ts / (tt + EPSD);
    float bt = (float)(rhoN / (rho + EPSD) * (alpha / (omega + EPSD)));
    float o = (float)omega;
#pragma unroll
    for (int i = 0; i < 4; ++i) pn[i] = r4[i] + bt * (p4[i] - o * v4[i]);
    st4(pout, e, pn);
}

static const int RHO_OFF[5] = { 0, 16, 2, 18, 4 };
static const int R0V_OFF[4] = { 32, 34, 48, 50 };
static const int TS_OFF[4]  = { 64, 66, 80, 82 };
static const int TT_OFF[4]  = { 96, 98, 112, 114 };

template<typename TV, int S>
static void run_all(const float* x_in, const float* b_in, const float* cen,
                    float* bufR0, float* bufR, float* bufP, float* x_out,
                    TV* bufV, bf16_t* bufT, double* acc, hipStream_t stream) {
    dim3 blk(BLK), grd(GRD);
    int nacc = S * REP;
    k_zero<<<dim3((nacc + 255) / 256), dim3(256), 0, stream>>>(acc, nacc);
    k_init<S><<<grd, blk, 0, stream>>>(x_in, b_in, cen, bufR0, acc, RHO_OFF[0]);

    const float* rcur = bufR0;   // iter 0: r = p = r0 (aliased reads)
    const float* pcur = bufR0;
    const float* xcur = x_in;
    for (int i = 0; i < 4; ++i) {
        k_spmv<TV, S><<<grd, blk, 0, stream>>>(pcur, bufR0, cen, bufV, acc,
                                               R0V_OFF[i]);
        k_st<TV, S><<<grd, blk, 0, stream>>>(rcur, bufV, cen, bufT, acc,
                                             RHO_OFF[i], R0V_OFF[i],
                                             TS_OFF[i], TT_OFF[i]);
        int storeR = (i < 3) ? 1 : 0;   // final iter: r', rho4, p' dead
        k_update<TV, S><<<grd, blk, 0, stream>>>(xcur, x_out, pcur, rcur, bufR,
                                                 bufV, bufT, bufR0, acc,
                                                 RHO_OFF[i], R0V_OFF[i],
                                                 TS_OFF[i], TT_OFF[i],
                                                 RHO_OFF[i + 1], storeR);
        if (i < 3)
            k_pupd<TV, S><<<grd, blk, 0, stream>>>(bufR, pcur, bufV, bufP, acc,
                                                   RHO_OFF[i], R0V_OFF[i],
                                                   TS_OFF[i], TT_OFF[i],
                                                   RHO_OFF[i + 1]);
        rcur = bufR; pcur = bufP; xcur = x_out;
    }
}

extern "C" void kernel_launch(void* const* d_in, const int* in_sizes, int n_in,
                              void* d_out, int out_size, void* d_ws, size_t ws_size,
                              hipStream_t stream) {
    // All tensors are float32 (per reference dtypes). Field homes:
    //   x  : d_out (f32, in-place across iterations)
    //   r0 : d_in[2] ('ref' input — unused by the math, restored every launch)
    //   r  : d_in[0] (x input; read elementwise in iter-0 k_update before write)
    //   p  : d_in[1] (b input; consumed in k_init)
    //   v  : d_ws (f32 if ws_size allows, else bf16)
    //   t  : d_ws (bf16 always — only feeds r' = s - o*t; 0.2% rel error is fine)
    const float* x_in = (const float*)d_in[0];
    const float* b_in = (const float*)d_in[1];
    const float* cen  = (const float*)d_in[3];
    float* bufR  = (float*)d_in[0];
    float* bufP  = (float*)d_in[1];
    float* bufR0 = (float*)d_in[2];
    float* x_out = (float*)d_out;

    double* acc = (double*)d_ws;
    const size_t F32F = (size_t)NELEM * 4, BF16F = (size_t)NELEM * 2;
    const size_t ACC16 = 16 * 1024, ACC1 = 1024;

    if (ws_size >= ACC16 + F32F + BF16F) {
        // tier B (~201.3 MB fields + 16 KB acc): v in f32, t in bf16, S=16
        char* base = (char*)d_ws + ACC16;
        float* bufV = (float*)base;
        bf16_t* bufT = (bf16_t*)(base + F32F);
        run_all<float, 16>(x_in, b_in, cen, bufR0, bufR, bufP, x_out, bufV, bufT,
                           acc, stream);
    } else if (ws_size >= ACC1 + F32F + BF16F) {
        // tier B fallback, S=1 (identical layout to previous round)
        char* base = (char*)d_ws + ACC1;
        float* bufV = (float*)base;
        bf16_t* bufT = (bf16_t*)(base + F32F);
        run_all<float, 1>(x_in, b_in, cen, bufR0, bufR, bufP, x_out, bufV, bufT,
                          acc, stream);
    } else if (ws_size >= ACC16 + 2 * BF16F) {
        // tier C (~134.2 MB fields + 16 KB acc): v and t in bf16, S=16
        char* base = (char*)d_ws + ACC16;
        bf16_t* bufV = (bf16_t*)base;
        bf16_t* bufT = bufV + NELEM;
        run_all<bf16_t, 16>(x_in, b_in, cen, bufR0, bufR, bufP, x_out, bufV, bufT,
                            acc, stream);
    } else {
        // tier C fallback, S=1
        char* base = (char*)d_ws + ACC1;
        bf16_t* bufV = (bf16_t*)base;
        bf16_t* bufT = bufV + NELEM;
        run_all<bf16_t, 1>(x_in, b_in, cen, bufR0, bufR, bufP, x_out, bufV, bufT,
                           acc, stream);
    }
}

// Round 3
// 2061.804 us; speedup vs baseline: 5.1069x; 1.8394x over previous
//
#include <hip/hip_runtime.h>

typedef unsigned short bf16_t;

#define HH 256
#define WW 256
#define ZZ 256
#define NELEM 33554432          /* 2*256^3 elements */
#define BLK   256
#define GRD   ((NELEM / 4) / BLK)   /* 32768 blocks; 4 f32 elems per thread */
#define EPSD  1e-6

// ---------- bf16 <-> f32 (for reduced-precision scratch fields only) ----------
__device__ __forceinline__ float bf2f(unsigned int s) {
    union { unsigned int u; float f; } c; c.u = s << 16; return c.f;
}
__device__ __forceinline__ unsigned int f2bf(float f) {
    union { float f; unsigned int u; } c; c.f = f;
    return (c.u + 0x7fffu + ((c.u >> 16) & 1u)) >> 16;   // RNE
}

// ---------- overloaded 4-wide field I/O ----------
__device__ __forceinline__ void ld4(const float* F, int e, float* o) {
    float4 v = *(const float4*)(F + e);
    o[0] = v.x; o[1] = v.y; o[2] = v.z; o[3] = v.w;
}
__device__ __forceinline__ void st4(float* F, int e, const float* o) {
    *(float4*)(F + e) = make_float4(o[0], o[1], o[2], o[3]);
}
__device__ __forceinline__ void ld4(const bf16_t* F, int e, float* o) {
    uint2 u = *(const uint2*)(F + e);
    o[0] = bf2f(u.x & 0xffffu); o[1] = bf2f(u.x >> 16);
    o[2] = bf2f(u.y & 0xffffu); o[3] = bf2f(u.y >> 16);
}
__device__ __forceinline__ void st4(bf16_t* F, int e, const float* o) {
    uint2 u;
    u.x = f2bf(o[0]) | (f2bf(o[1]) << 16);
    u.y = f2bf(o[2]) | (f2bf(o[3]) << 16);
    *(uint2*)(F + e) = u;
}
__device__ __forceinline__ float lds1(const float* F, int e)  { return F[e]; }
__device__ __forceinline__ float lds1(const bf16_t* F, int e) { return bf2f(F[e]); }
__device__ __forceinline__ void zero4(float* o) {
#pragma unroll
    for (int i = 0; i < 4; ++i) o[i] = 0.f;
}

// 7-point stencil, zero Dirichlet boundaries; c[] = already-loaded center row.
template<typename T>
__device__ __forceinline__ void stencil4(const T* F, int e, int w, int h, int z,
                                         float cw, const float* c, float* out) {
    float wm[4], wp[4], hm[4], hp[4];
    if (w > 0)      ld4(F, e - ZZ, wm);      else zero4(wm);
    if (w < WW - 1) ld4(F, e + ZZ, wp);      else zero4(wp);
    if (h > 0)      ld4(F, e - WW * ZZ, hm); else zero4(hm);
    if (h < HH - 1) ld4(F, e + WW * ZZ, hp); else zero4(hp);
    float zm = (z > 0)      ? lds1(F, e - 1) : 0.f;
    float zp = (z < ZZ - 4) ? lds1(F, e + 4) : 0.f;
#pragma unroll
    for (int i = 0; i < 4; ++i) {
        float left  = (i == 0) ? zm : c[i - 1];
        float right = (i == 3) ? zp : c[i + 1];
        out[i] = cw * c[i] - left - right - wm[i] - wp[i] - hm[i] - hp[i];
    }
}

__device__ __forceinline__ double dot4d(const float* a, const float* b) {
    double s = 0.0;
#pragma unroll
    for (int i = 0; i < 4; ++i) s += (double)a[i] * (double)b[i];
    return s;
}

// ---------------------------------------------------------------------------
// Accumulator region layout (doubles):
//   [0, S*REP)        : S replicas of the 1024 B unit-separated block
//                       (atomic targets; layout identical to round 1/2):
//     unit0: rho0@0  rho2@2  rho4@4      unit1: rho1@16 rho3@18
//     unit2: r0v0@32 r0v1@34             unit3: r0v2@48 r0v3@50
//     unit4: ts0@64  ts1@66              unit5: ts2@80  ts3@82
//     unit6: tt0@96  tt1@98              unit7: tt2@112 tt3@114
//   [S*REP, S*REP+8)  : COEF line — written ONLY by 1-wave micro-kernels
//                       between big dispatches, read-only for big kernels.
//                       Disjoint from every atomic-target line (round-0
//                       invariant preserved trivially).
// Round-2 lesson: consumers doing rd_acc<16> (80 uniform f64 loads/thread,
// 10.5M same-line requests device-wide) stalled every consumer kernel
// (k_pupd: 341 us @ 980 GB/s, VALUBusy 12%). The micro-kernels collapse the
// replicas ONCE and store alpha/omega/beta; consumers load 1-2 doubles.
// ---------------------------------------------------------------------------
#define REP 128   /* doubles per replica */
#define CO_ALPHA 0   /* + bat */
#define CO_OMEGA 2
#define CO_BETA  4
#define CO_RHO   6

// ---------- reductions (f64, one replicated atomic per block, per batch) ----
__device__ __forceinline__ double wave_red(double v) {
#pragma unroll
    for (int o = 32; o > 0; o >>= 1) v += __shfl_down(v, o, 64);
    return v;
}
__device__ __forceinline__ void block_red1(double v0, double* d0) {
    v0 = wave_red(v0);
    __shared__ double sm0[4];
    int lane = threadIdx.x & 63, wid = threadIdx.x >> 6;
    if (lane == 0) sm0[wid] = v0;
    __syncthreads();
    if (threadIdx.x == 0) atomicAdd(d0, sm0[0] + sm0[1] + sm0[2] + sm0[3]);
}
__device__ __forceinline__ void block_red2(double v0, double v1, double* d0, double* d1) {
    v0 = wave_red(v0); v1 = wave_red(v1);
    __shared__ double sm0[4], sm1[4];
    int lane = threadIdx.x & 63, wid = threadIdx.x >> 6;
    if (lane == 0) { sm0[wid] = v0; sm1[wid] = v1; }
    __syncthreads();
    if (threadIdx.x == 0) {
        atomicAdd(d0, sm0[0] + sm0[1] + sm0[2] + sm0[3]);
        atomicAdd(d1, sm1[0] + sm1[1] + sm1[2] + sm1[3]);
    }
}

#define DECODE()                                            \
    int gid = blockIdx.x * BLK + threadIdx.x;               \
    int e = gid << 2;                                       \
    int z = e & (ZZ - 1);                                   \
    int w = (e >> 8) & (WW - 1);                            \
    int h = (e >> 16) & (HH - 1);                           \
    int bat = e >> 24;

__global__ void k_zero(double* acc, int n) {
    int i = blockIdx.x * 256 + threadIdx.x;
    if (i < n) acc[i] = 0.0;
}

// ---------- 1-wave coefficient micro-kernels ----------
// Lanes 0..15 load the 16 replicas of (slotA, bat0), 16..31 (slotA, bat1),
// 32..47 (slotB, bat0), 48..63 (slotB, bat1); xor-tree within 16-lane groups.
template<int S>
__device__ __forceinline__ double collapse2(const double* acc, int offA, int offB,
                                            int lane) {
    int grp = lane >> 4, rep = lane & 15, bat = grp & 1;
    int off = ((grp < 2) ? offA : offB) + bat;
    double v = (rep < S) ? acc[rep * REP + off] : 0.0;
    v += __shfl_xor(v, 1, 64);
    v += __shfl_xor(v, 2, 64);
    v += __shfl_xor(v, 4, 64);
    v += __shfl_xor(v, 8, 64);
    return v;   // every lane of a group holds that group's sum
}

template<int S>
__global__ void k_alpha(double* acc, int oRho, int oR0V) {
    int lane = threadIdx.x;
    double v = collapse2<S>(acc, oRho, oR0V, lane);
    double rho = __shfl(v, (lane & 1) << 4, 64);
    double r0v = __shfl(v, 32 + ((lane & 1) << 4), 64);
    double* co = acc + S * REP;
    if (lane < 2) {
        co[CO_ALPHA + lane] = rho / (r0v + EPSD);
        co[CO_RHO + lane]   = rho;
    }
}

template<int S>
__global__ void k_omega(double* acc, int oTS, int oTT) {
    int lane = threadIdx.x;
    double v = collapse2<S>(acc, oTS, oTT, lane);
    double ts = __shfl(v, (lane & 1) << 4, 64);
    double tt = __shfl(v, 32 + ((lane & 1) << 4), 64);
    double* co = acc + S * REP;
    if (lane < 2) co[CO_OMEGA + lane] = ts / (tt + EPSD);
}

template<int S>
__global__ void k_betak(double* acc, int oRhoN) {
    int lane = threadIdx.x;
    double v = collapse2<S>(acc, oRhoN, oRhoN, lane);   // groups 2,3 redundant
    double rhoN = __shfl(v, (lane & 1) << 4, 64);
    double* co = acc + S * REP;
    if (lane < 2) {
        double rho   = co[CO_RHO + lane];
        double alpha = co[CO_ALPHA + lane];
        double omega = co[CO_OMEGA + lane];
        co[CO_BETA + lane] = rhoN / (rho + EPSD) * (alpha / (omega + EPSD));
    }
}

// ---------- big kernels ----------

// r0 = b - S(x); rho0 += r0.r0
template<int S>
__global__ void k_init(const float* xf, const float* bf, const float* cen,
                       float* r0, double* acc, int oRho0) {
    DECODE();
    float cw = cen[h * WW + w];
    float c[4], st[4], b4[4], r[4];
    ld4(xf, e, c);
    stencil4(xf, e, w, h, z, cw, c, st);
    ld4(bf, e, b4);
#pragma unroll
    for (int i = 0; i < 4; ++i) r[i] = b4[i] - st[i];
    st4(r0, e, r);
    int sub = blockIdx.x & (S - 1);
    block_red1(dot4d(r, r), &acc[sub * REP + oRho0 + bat]);
}

// v = S(p); dot_r0v += r0.v  (all loads issued before the v store)
template<typename TV, int S>
__global__ void k_spmv(const float* pf, const float* r0, const float* cen,
                       TV* vf, double* acc, int oR0V) {
    DECODE();
    float cw = cen[h * WW + w];
    float c[4], st[4], r04[4];
    ld4(pf, e, c);
    ld4(r0, e, r04);
    stencil4(pf, e, w, h, z, cw, c, st);
    st4(vf, e, st);
    int sub = blockIdx.x & (S - 1);
    block_red1(dot4d(r04, st), &acc[sub * REP + oR0V + bat]);
}

// s = r - a*v; t = S(r) - a*S(v)  (stencil linearity); store t (bf16);
// dot_ts += t.s; dot_tt += t.t.  alpha comes precomputed from k_alpha.
template<typename TV, int S>
__global__ void k_st(const float* rf, const TV* vf, const float* cen, bf16_t* tf,
                     const double* co, double* acc, int oTS, int oTT) {
    DECODE();
    float cw = cen[h * WW + w];
    float rc[4], vc[4], str[4], stv[4], s4[4], t4[4];
    ld4(rf, e, rc);
    ld4(vf, e, vc);
    stencil4(rf, e, w, h, z, cw, rc, str);
    stencil4(vf, e, w, h, z, cw, vc, stv);
    float a = (float)co[CO_ALPHA + bat];
#pragma unroll
    for (int i = 0; i < 4; ++i) {
        s4[i] = rc[i] - a * vc[i];
        t4[i] = str[i] - a * stv[i];
    }
    st4(tf, e, t4);
    int sub = blockIdx.x & (S - 1);
    block_red2(dot4d(t4, s4), dot4d(t4, t4),
               &acc[sub * REP + oTS + bat], &acc[sub * REP + oTT + bat]);
}

// x' = x + a*p + o*s; r' = s - o*t; rho_next += r0.r'   (pure elementwise)
// NOTE: no __restrict__ — xin/rout alias on iter 0, xin/xout and rf/rout on
// iters>=1; same-index read-then-write. ALL field loads are issued before
// any store so program-order aliasing constraints impose no waits.
template<typename TV, int S>
__global__ void k_update(const float* xin, float* xout, const float* pf,
                         const float* rf, float* rout, const TV* vf,
                         const bf16_t* tf, const float* r0f,
                         const double* co, double* acc, int oRhoN, int storeR) {
    DECODE();
    (void)z; (void)w; (void)h;
    float x4[4], p4[4], r4[4], v4[4], t4[4], s4[4], xo[4], rn[4], r04[4];
    ld4(xin, e, x4); ld4(pf, e, p4); ld4(rf, e, r4);
    ld4(vf, e, v4);  ld4(tf, e, t4);
    if (storeR) ld4(r0f, e, r04);           // hoisted above all stores
    float a = (float)co[CO_ALPHA + bat];
    float o = (float)co[CO_OMEGA + bat];
#pragma unroll
    for (int i = 0; i < 4; ++i) {
        s4[i] = r4[i] - a * v4[i];
        xo[i] = x4[i] + a * p4[i] + o * s4[i];
        rn[i] = s4[i] - o * t4[i];
    }
    st4(xout, e, xo);
    if (storeR) {
        st4(rout, e, rn);
        int sub = blockIdx.x & (S - 1);
        block_red1(dot4d(r04, rn), &acc[sub * REP + oRhoN + bat]);
    }
}

// p' = r' + beta*(p - o*v)  — beta, omega precomputed by k_betak/k_omega.
// (pin/pout alias on iters >= 1 — no __restrict__)
template<typename TV>
__global__ void k_pupd(const float* rf, const float* pin, const TV* vf, float* pout,
                       const double* co) {
    DECODE();
    (void)z; (void)w; (void)h;
    float r4[4], p4[4], v4[4], pn[4];
    ld4(rf, e, r4); ld4(pin, e, p4); ld4(vf, e, v4);
    float o  = (float)co[CO_OMEGA + bat];
    float bt = (float)co[CO_BETA + bat];
#pragma unroll
    for (int i = 0; i < 4; ++i) pn[i] = r4[i] + bt * (p4[i] - o * v4[i]);
    st4(pout, e, pn);
}

static const int RHO_OFF[5] = { 0, 16, 2, 18, 4 };
static const int R0V_OFF[4] = { 32, 34, 48, 50 };
static const int TS_OFF[4]  = { 64, 66, 80, 82 };
static const int TT_OFF[4]  = { 96, 98, 112, 114 };

template<typename TV, int S>
static void run_all(const float* x_in, const float* b_in, const float* cen,
                    float* bufR0, float* bufR, float* bufP, float* x_out,
                    TV* bufV, bf16_t* bufT, double* acc, hipStream_t stream) {
    dim3 blk(BLK), grd(GRD);
    dim3 one(1), wv(64);
    const double* co = acc + S * REP;
    int nacc = S * REP + 8;
    k_zero<<<dim3((nacc + 255) / 256), dim3(256), 0, stream>>>(acc, nacc);
    k_init<S><<<grd, blk, 0, stream>>>(x_in, b_in, cen, bufR0, acc, RHO_OFF[0]);

    const float* rcur = bufR0;   // iter 0: r = p = r0 (aliased reads)
    const float* pcur = bufR0;
    const float* xcur = x_in;
    for (int i = 0; i < 4; ++i) {
        k_spmv<TV, S><<<grd, blk, 0, stream>>>(pcur, bufR0, cen, bufV, acc,
                                               R0V_OFF[i]);
        k_alpha<S><<<one, wv, 0, stream>>>(acc, RHO_OFF[i], R0V_OFF[i]);
        k_st<TV, S><<<grd, blk, 0, stream>>>(rcur, bufV, cen, bufT, co, acc,
                                             TS_OFF[i], TT_OFF[i]);
        k_omega<S><<<one, wv, 0, stream>>>(acc, TS_OFF[i], TT_OFF[i]);
        int storeR = (i < 3) ? 1 : 0;   // final iter: r', rho4, p' dead
        k_update<TV, S><<<grd, blk, 0, stream>>>(xcur, x_out, pcur, rcur, bufR,
                                                 bufV, bufT, bufR0, co, acc,
                                                 RHO_OFF[i + 1], storeR);
        if (i < 3) {
            k_betak<S><<<one, wv, 0, stream>>>(acc, RHO_OFF[i + 1]);
            k_pupd<TV><<<grd, blk, 0, stream>>>(bufR, pcur, bufV, bufP, co);
        }
        rcur = bufR; pcur = bufP; xcur = x_out;
    }
}

extern "C" void kernel_launch(void* const* d_in, const int* in_sizes, int n_in,
                              void* d_out, int out_size, void* d_ws, size_t ws_size,
                              hipStream_t stream) {
    // All tensors are float32 (per reference dtypes). Field homes:
    //   x  : d_out (f32, in-place across iterations)
    //   r0 : d_in[2] ('ref' input — unused by the math, restored every launch)
    //   r  : d_in[0] (x input; read elementwise in iter-0 k_update before write)
    //   p  : d_in[1] (b input; consumed in k_init)
    //   v  : d_ws (f32 if ws_size allows, else bf16)
    //   t  : d_ws (bf16 always — only feeds r' = s - o*t; 0.2% rel error is fine)
    const float* x_in = (const float*)d_in[0];
    const float* b_in = (const float*)d_in[1];
    const float* cen  = (const float*)d_in[3];
    float* bufR  = (float*)d_in[0];
    float* bufP  = (float*)d_in[1];
    float* bufR0 = (float*)d_in[2];
    float* x_out = (float*)d_out;

    double* acc = (double*)d_ws;
    const size_t F32F = (size_t)NELEM * 4, BF16F = (size_t)NELEM * 2;
    const size_t ACC16 = 16 * 1024 + 1024;   // replicas + COEF line (+pad)
    const size_t ACC1  = 1024 + 1024;

    if (ws_size >= ACC16 + F32F + BF16F) {
        // tier B (~201.3 MB fields + 17 KB acc): v in f32, t in bf16, S=16
        char* base = (char*)d_ws + ACC16;
        float* bufV = (float*)base;
        bf16_t* bufT = (bf16_t*)(base + F32F);
        run_all<float, 16>(x_in, b_in, cen, bufR0, bufR, bufP, x_out, bufV, bufT,
                           acc, stream);
    } else if (ws_size >= ACC1 + F32F + BF16F) {
        // tier B fallback, S=1
        char* base = (char*)d_ws + ACC1;
        float* bufV = (float*)base;
        bf16_t* bufT = (bf16_t*)(base + F32F);
        run_all<float, 1>(x_in, b_in, cen, bufR0, bufR, bufP, x_out, bufV, bufT,
                          acc, stream);
    } else if (ws_size >= ACC16 + 2 * BF16F) {
        // tier C (~134.2 MB fields + 17 KB acc): v and t in bf16, S=16
        char* base = (char*)d_ws + ACC16;
        bf16_t* bufV = (bf16_t*)base;
        bf16_t* bufT = bufV + NELEM;
        run_all<bf16_t, 16>(x_in, b_in, cen, bufR0, bufR, bufP, x_out, bufV, bufT,
                            acc, stream);
    } else {
        // tier C fallback, S=1
        char* base = (char*)d_ws + ACC1;
        bf16_t* bufV = (bf16_t*)base;
        bf16_t* bufT = bufV + NELEM;
        run_all<bf16_t, 1>(x_in, b_in, cen, bufR0, bufR, bufP, x_out, bufV, bufT,
                           acc, stream);
    }
}

// Round 4
// 1835.251 us; speedup vs baseline: 5.7373x; 1.1234x over previous
//
#include <hip/hip_runtime.h>

typedef _Float16 fp16_t;
typedef _Float16 half4_t __attribute__((ext_vector_type(4)));

#define HH 256
#define WW 256
#define ZZ 256
#define NELEM 33554432          /* 2*256^3 elements */
#define BLK   256
#define GRD   ((NELEM / 4) / BLK)   /* 32768 blocks; 4 f32 elems per thread */
#define EPSD  1e-6

/* fp16 scratch fields are stored scaled by 1/64 (exact power of 2):
   range extends to +/-4.2e6, precision is fp16's 4.9e-4 relative —
   8x better than the bf16 previously used for t, and the scale costs
   one multiply at load/store. */
#define HSC_ST 0.015625f   /* 1/64 on store */
#define HSC_LD 64.0f       /* x64 on load  */

// ---------- overloaded 4-wide field I/O ----------
__device__ __forceinline__ void ld4(const float* F, int e, float* o) {
    float4 v = *(const float4*)(F + e);
    o[0] = v.x; o[1] = v.y; o[2] = v.z; o[3] = v.w;
}
__device__ __forceinline__ void st4(float* F, int e, const float* o) {
    *(float4*)(F + e) = make_float4(o[0], o[1], o[2], o[3]);
}
__device__ __forceinline__ void ld4(const fp16_t* F, int e, float* o) {
    half4_t v = *(const half4_t*)(F + e);
#pragma unroll
    for (int i = 0; i < 4; ++i) o[i] = (float)v[i] * HSC_LD;
}
__device__ __forceinline__ void st4(fp16_t* F, int e, const float* o) {
    half4_t v;
#pragma unroll
    for (int i = 0; i < 4; ++i) v[i] = (fp16_t)(o[i] * HSC_ST);
    *(half4_t*)(F + e) = v;
}
__device__ __forceinline__ float lds1(const float* F, int e)  { return F[e]; }
__device__ __forceinline__ float lds1(const fp16_t* F, int e) { return (float)F[e] * HSC_LD; }
__device__ __forceinline__ void zero4(float* o) {
#pragma unroll
    for (int i = 0; i < 4; ++i) o[i] = 0.f;
}

// 7-point stencil, zero Dirichlet boundaries; c[] = already-loaded center row.
template<typename T>
__device__ __forceinline__ void stencil4(const T* F, int e, int w, int h, int z,
                                         float cw, const float* c, float* out) {
    float wm[4], wp[4], hm[4], hp[4];
    if (w > 0)      ld4(F, e - ZZ, wm);      else zero4(wm);
    if (w < WW - 1) ld4(F, e + ZZ, wp);      else zero4(wp);
    if (h > 0)      ld4(F, e - WW * ZZ, hm); else zero4(hm);
    if (h < HH - 1) ld4(F, e + WW * ZZ, hp); else zero4(hp);
    float zm = (z > 0)      ? lds1(F, e - 1) : 0.f;
    float zp = (z < ZZ - 4) ? lds1(F, e + 4) : 0.f;
#pragma unroll
    for (int i = 0; i < 4; ++i) {
        float left  = (i == 0) ? zm : c[i - 1];
        float right = (i == 3) ? zp : c[i + 1];
        out[i] = cw * c[i] - left - right - wm[i] - wp[i] - hm[i] - hp[i];
    }
}

__device__ __forceinline__ double dot4d(const float* a, const float* b) {
    double s = 0.0;
#pragma unroll
    for (int i = 0; i < 4; ++i) s += (double)a[i] * (double)b[i];
    return s;
}

// ---------------------------------------------------------------------------
// Accumulator region layout (doubles):
//   [0, S*REP)        : S replicas of the 1024 B unit-separated block
//                       (atomic targets; layout identical to rounds 1-3):
//     unit0: rho0@0  rho2@2  rho4@4      unit1: rho1@16 rho3@18
//     unit2: r0v0@32 r0v1@34             unit3: r0v2@48 r0v3@50
//     unit4: ts0@64  ts1@66              unit5: ts2@80  ts3@82
//     unit6: tt0@96  tt1@98              unit7: tt2@112 tt3@114
//   [S*REP, S*REP+8)  : COEF line — written ONLY by 1-wave micro-kernels
//                       between big dispatches, read-only for big kernels.
// Round-0 lesson: atomic-target lines disjoint from broadcast-read lines.
// Round-1 lesson: replicate atomics S=16 to break the single-line RMW chain.
// Round-2 lesson: collapse replicas ONCE in a micro-kernel; consumers load
//                 1-2 coefficient doubles instead of 32-80 replica loads.
// ---------------------------------------------------------------------------
#define REP 128   /* doubles per replica */
#define CO_ALPHA 0   /* + bat */
#define CO_OMEGA 2
#define CO_BETA  4
#define CO_RHO   6

// ---------- reductions (f64, one replicated atomic per block, per batch) ----
__device__ __forceinline__ double wave_red(double v) {
#pragma unroll
    for (int o = 32; o > 0; o >>= 1) v += __shfl_down(v, o, 64);
    return v;
}
__device__ __forceinline__ void block_red1(double v0, double* d0) {
    v0 = wave_red(v0);
    __shared__ double sm0[4];
    int lane = threadIdx.x & 63, wid = threadIdx.x >> 6;
    if (lane == 0) sm0[wid] = v0;
    __syncthreads();
    if (threadIdx.x == 0) atomicAdd(d0, sm0[0] + sm0[1] + sm0[2] + sm0[3]);
}
__device__ __forceinline__ void block_red2(double v0, double v1, double* d0, double* d1) {
    v0 = wave_red(v0); v1 = wave_red(v1);
    __shared__ double sm0[4], sm1[4];
    int lane = threadIdx.x & 63, wid = threadIdx.x >> 6;
    if (lane == 0) { sm0[wid] = v0; sm1[wid] = v1; }
    __syncthreads();
    if (threadIdx.x == 0) {
        atomicAdd(d0, sm0[0] + sm0[1] + sm0[2] + sm0[3]);
        atomicAdd(d1, sm1[0] + sm1[1] + sm1[2] + sm1[3]);
    }
}

#define DECODE()                                            \
    int gid = blockIdx.x * BLK + threadIdx.x;               \
    int e = gid << 2;                                       \
    int z = e & (ZZ - 1);                                   \
    int w = (e >> 8) & (WW - 1);                            \
    int h = (e >> 16) & (HH - 1);                           \
    int bat = e >> 24;

__global__ void k_zero(double* acc, int n) {
    int i = blockIdx.x * 256 + threadIdx.x;
    if (i < n) acc[i] = 0.0;
}

// ---------- 1-wave coefficient micro-kernels ----------
// Lanes 0..15 load the 16 replicas of (slotA, bat0), 16..31 (slotA, bat1),
// 32..47 (slotB, bat0), 48..63 (slotB, bat1); xor-tree within 16-lane groups.
template<int S>
__device__ __forceinline__ double collapse2(const double* acc, int offA, int offB,
                                            int lane) {
    int grp = lane >> 4, rep = lane & 15, bat = grp & 1;
    int off = ((grp < 2) ? offA : offB) + bat;
    double v = (rep < S) ? acc[rep * REP + off] : 0.0;
    v += __shfl_xor(v, 1, 64);
    v += __shfl_xor(v, 2, 64);
    v += __shfl_xor(v, 4, 64);
    v += __shfl_xor(v, 8, 64);
    return v;   // every lane of a group holds that group's sum
}

template<int S>
__global__ void k_alpha(double* acc, int oRho, int oR0V) {
    int lane = threadIdx.x;
    double v = collapse2<S>(acc, oRho, oR0V, lane);
    double rho = __shfl(v, (lane & 1) << 4, 64);
    double r0v = __shfl(v, 32 + ((lane & 1) << 4), 64);
    double* co = acc + S * REP;
    if (lane < 2) {
        co[CO_ALPHA + lane] = rho / (r0v + EPSD);
        co[CO_RHO + lane]   = rho;
    }
}

template<int S>
__global__ void k_omega(double* acc, int oTS, int oTT) {
    int lane = threadIdx.x;
    double v = collapse2<S>(acc, oTS, oTT, lane);
    double ts = __shfl(v, (lane & 1) << 4, 64);
    double tt = __shfl(v, 32 + ((lane & 1) << 4), 64);
    double* co = acc + S * REP;
    if (lane < 2) co[CO_OMEGA + lane] = ts / (tt + EPSD);
}

template<int S>
__global__ void k_betak(double* acc, int oRhoN) {
    int lane = threadIdx.x;
    double v = collapse2<S>(acc, oRhoN, oRhoN, lane);   // groups 2,3 redundant
    double rhoN = __shfl(v, (lane & 1) << 4, 64);
    double* co = acc + S * REP;
    if (lane < 2) {
        double rho   = co[CO_RHO + lane];
        double alpha = co[CO_ALPHA + lane];
        double omega = co[CO_OMEGA + lane];
        co[CO_BETA + lane] = rhoN / (rho + EPSD) * (alpha / (omega + EPSD));
    }
}

// ---------- big kernels ----------

// r0 = b - S(x); rho0 += r0.r0
template<int S>
__global__ void k_init(const float* xf, const float* bf, const float* cen,
                       float* r0, double* acc, int oRho0) {
    DECODE();
    float cw = cen[h * WW + w];
    float c[4], st[4], b4[4], r[4];
    ld4(xf, e, c);
    stencil4(xf, e, w, h, z, cw, c, st);
    ld4(bf, e, b4);
#pragma unroll
    for (int i = 0; i < 4; ++i) r[i] = b4[i] - st[i];
    st4(r0, e, r);
    int sub = blockIdx.x & (S - 1);
    block_red1(dot4d(r, r), &acc[sub * REP + oRho0 + bat]);
}

// v = S(p); dot_r0v += r0.v  (all loads issued before the v store; the
// reduction uses the full-precision stencil value, pre-quantization)
template<int S>
__global__ void k_spmv(const float* pf, const float* r0, const float* cen,
                       fp16_t* vf, double* acc, int oR0V) {
    DECODE();
    float cw = cen[h * WW + w];
    float c[4], st[4], r04[4];
    ld4(pf, e, c);
    ld4(r0, e, r04);
    stencil4(pf, e, w, h, z, cw, c, st);
    st4(vf, e, st);
    int sub = blockIdx.x & (S - 1);
    block_red1(dot4d(r04, st), &acc[sub * REP + oR0V + bat]);
}

// s = r - a*v; t = S(r) - a*S(v)  (stencil linearity); store t (fp16);
// dot_ts += t.s; dot_tt += t.t.  alpha comes precomputed from k_alpha.
template<int S>
__global__ void k_st(const float* rf, const fp16_t* vf, const float* cen,
                     fp16_t* tf, const double* co, double* acc, int oTS, int oTT) {
    DECODE();
    float cw = cen[h * WW + w];
    float rc[4], vc[4], str[4], stv[4], s4[4], t4[4];
    ld4(rf, e, rc);
    ld4(vf, e, vc);
    stencil4(rf, e, w, h, z, cw, rc, str);
    stencil4(vf, e, w, h, z, cw, vc, stv);
    float a = (float)co[CO_ALPHA + bat];
#pragma unroll
    for (int i = 0; i < 4; ++i) {
        s4[i] = rc[i] - a * vc[i];
        t4[i] = str[i] - a * stv[i];
    }
    st4(tf, e, t4);
    int sub = blockIdx.x & (S - 1);
    block_red2(dot4d(t4, s4), dot4d(t4, t4),
               &acc[sub * REP + oTS + bat], &acc[sub * REP + oTT + bat]);
}

// x' = x + a*p + o*s; r' = s - o*t; rho_next += r0.r'   (pure elementwise)
// NOTE: no __restrict__ — xin/rout alias on iter 0, xin/xout and rf/rout on
// iters>=1; same-index read-then-write. ALL field loads are issued before
// any store so program-order aliasing constraints impose no waits.
template<int S>
__global__ void k_update(const float* xin, float* xout, const float* pf,
                         const float* rf, float* rout, const fp16_t* vf,
                         const fp16_t* tf, const float* r0f,
                         const double* co, double* acc, int oRhoN, int storeR) {
    DECODE();
    (void)z; (void)w; (void)h;
    float x4[4], p4[4], r4[4], v4[4], t4[4], s4[4], xo[4], rn[4], r04[4];
    ld4(xin, e, x4); ld4(pf, e, p4); ld4(rf, e, r4);
    ld4(vf, e, v4);  ld4(tf, e, t4);
    if (storeR) ld4(r0f, e, r04);           // hoisted above all stores
    float a = (float)co[CO_ALPHA + bat];
    float o = (float)co[CO_OMEGA + bat];
#pragma unroll
    for (int i = 0; i < 4; ++i) {
        s4[i] = r4[i] - a * v4[i];
        xo[i] = x4[i] + a * p4[i] + o * s4[i];
        rn[i] = s4[i] - o * t4[i];
    }
    st4(xout, e, xo);
    if (storeR) {
        st4(rout, e, rn);
        int sub = blockIdx.x & (S - 1);
        block_red1(dot4d(r04, rn), &acc[sub * REP + oRhoN + bat]);
    }
}

// p' = r' + beta*(p - o*v)  — beta, omega precomputed by k_betak/k_omega.
// (pin/pout alias on iters >= 1 — no __restrict__)
__global__ void k_pupd(const float* rf, const float* pin, const fp16_t* vf,
                       float* pout, const double* co) {
    DECODE();
    (void)z; (void)w; (void)h;
    float r4[4], p4[4], v4[4], pn[4];
    ld4(rf, e, r4); ld4(pin, e, p4); ld4(vf, e, v4);
    float o  = (float)co[CO_OMEGA + bat];
    float bt = (float)co[CO_BETA + bat];
#pragma unroll
    for (int i = 0; i < 4; ++i) pn[i] = r4[i] + bt * (p4[i] - o * v4[i]);
    st4(pout, e, pn);
}

static const int RHO_OFF[5] = { 0, 16, 2, 18, 4 };
static const int R0V_OFF[4] = { 32, 34, 48, 50 };
static const int TS_OFF[4]  = { 64, 66, 80, 82 };
static const int TT_OFF[4]  = { 96, 98, 112, 114 };

template<int S>
static void run_all(const float* x_in, const float* b_in, const float* cen,
                    float* bufR0, float* bufR, float* bufP, float* x_out,
                    fp16_t* bufV, fp16_t* bufT, double* acc, hipStream_t stream) {
    dim3 blk(BLK), grd(GRD);
    dim3 one(1), wv(64);
    const double* co = acc + S * REP;
    int nacc = S * REP + 8;
    k_zero<<<dim3((nacc + 255) / 256), dim3(256), 0, stream>>>(acc, nacc);
    k_init<S><<<grd, blk, 0, stream>>>(x_in, b_in, cen, bufR0, acc, RHO_OFF[0]);

    const float* rcur = bufR0;   // iter 0: r = p = r0 (aliased reads)
    const float* pcur = bufR0;
    const float* xcur = x_in;
    for (int i = 0; i < 4; ++i) {
        k_spmv<S><<<grd, blk, 0, stream>>>(pcur, bufR0, cen, bufV, acc,
                                           R0V_OFF[i]);
        k_alpha<S><<<one, wv, 0, stream>>>(acc, RHO_OFF[i], R0V_OFF[i]);
        k_st<S><<<grd, blk, 0, stream>>>(rcur, bufV, cen, bufT, co, acc,
                                         TS_OFF[i], TT_OFF[i]);
        k_omega<S><<<one, wv, 0, stream>>>(acc, TS_OFF[i], TT_OFF[i]);
        int storeR = (i < 3) ? 1 : 0;   // final iter: r', rho4, p' dead
        k_update<S><<<grd, blk, 0, stream>>>(xcur, x_out, pcur, rcur, bufR,
                                             bufV, bufT, bufR0, co, acc,
                                             RHO_OFF[i + 1], storeR);
        if (i < 3) {
            k_betak<S><<<one, wv, 0, stream>>>(acc, RHO_OFF[i + 1]);
            k_pupd<<<grd, blk, 0, stream>>>(bufR, pcur, bufV, bufP, co);
        }
        rcur = bufR; pcur = bufP; xcur = x_out;
    }
}

extern "C" void kernel_launch(void* const* d_in, const int* in_sizes, int n_in,
                              void* d_out, int out_size, void* d_ws, size_t ws_size,
                              hipStream_t stream) {
    // All tensors are float32 (per reference dtypes). Field homes:
    //   x  : d_out (f32, in-place across iterations)
    //   r0 : d_in[2] ('ref' input — unused by the math, restored every launch)
    //   r  : d_in[0] (x input; read elementwise in iter-0 k_update before write)
    //   p  : d_in[1] (b input; consumed in k_init)
    //   v  : d_ws, fp16 scaled 1/64 (was f32 — halves the v stream, 4 passes)
    //   t  : d_ws, fp16 scaled 1/64 (was bf16 — same bytes, 8x more mantissa)
    const float* x_in = (const float*)d_in[0];
    const float* b_in = (const float*)d_in[1];
    const float* cen  = (const float*)d_in[3];
    float* bufR  = (float*)d_in[0];
    float* bufP  = (float*)d_in[1];
    float* bufR0 = (float*)d_in[2];
    float* x_out = (float*)d_out;

    double* acc = (double*)d_ws;
    const size_t FP16F = (size_t)NELEM * 2;          // 67.1 MB per fp16 field
    const size_t ACC16 = 16 * 1024 + 1024;           // replicas + COEF line
    const size_t ACC1  = 1024 + 1024;

    if (ws_size >= ACC16 + 2 * FP16F) {
        // primary (~134.2 MB fields + 17 KB acc): v,t fp16, S=16
        char* base = (char*)d_ws + ACC16;
        fp16_t* bufV = (fp16_t*)base;
        fp16_t* bufT = bufV + NELEM;
        run_all<16>(x_in, b_in, cen, bufR0, bufR, bufP, x_out, bufV, bufT,
                    acc, stream);
    } else {
        // fallback (~134.2 MB + 2 KB): same fields, S=1 replication
        char* base = (char*)d_ws + ACC1;
        fp16_t* bufV = (fp16_t*)base;
        fp16_t* bufT = bufV + NELEM;
        run_all<1>(x_in, b_in, cen, bufR0, bufR, bufP, x_out, bufV, bufT,
                   acc, stream);
    }
}